// Round 13
// baseline (605.355 us; speedup 1.0000x reference)
//
#include <hip/hip_runtime.h>

// TreeTransformer on MI355X: bf16 MFMA pipeline.
// B=32,A=64 -> S=2048 sequences, N=121 tokens, H=128, heads=4(hd=32), NL=2, OUT=256.
// r1-r6: swapped-operand attn + fused blockln (channel-partitioned).  [594us]
// r7/r8/r10: occupancy experiments REGRESSED (dup fetch / write frag / spill).
// r9: qmt/mt unroll-2 ILP. attn 114.5us.  <- attn accepted
// r11: outgemm XCD-swizzled (WO slice 1 fetch/XCD), convw float4.  [581us]
// r12: blockln 64-token blocks (grid 3872): LDS 69632->34816 -> 3 WG/CU
//      (launch_bounds(256,3); NOT 4 -> 128-VGPR cap would spill, r10 lesson).
//      Traffic-clean occupancy: no inter-block sharing except L2-resident
//      weights; O/X read exactly once.  [3rd submission: rounds 11+12 were
//      container-acquisition failures; audit found no hang/OOB mechanism.
//      If this fails again -> kernel-correlated, revert to r11 base.]

typedef unsigned short u16;
typedef __attribute__((ext_vector_type(8))) short bf16x8;  // 8 bf16 (4 VGPRs)
typedef __attribute__((ext_vector_type(4))) float f32x4;
typedef __attribute__((ext_vector_type(4))) unsigned int u32x4;
typedef __attribute__((ext_vector_type(2))) unsigned int u32x2;

#define NTOK 121
#define HD 128
#define S_TOT 2048
#define EPSF 1e-5f

__device__ inline u16 f2bf(float f) {  // round-to-nearest-even fp32->bf16
  unsigned u = __float_as_uint(f);
  return (u16)((u + 0x7FFFu + ((u >> 16) & 1u)) >> 16);
}
__device__ inline float bf2f(u16 h) { return __uint_as_float(((unsigned)h) << 16); }
__device__ inline float bfu32lo(unsigned u) { return __uint_as_float(u << 16); }
__device__ inline float bfu32hi(unsigned u) { return __uint_as_float(u & 0xffff0000u); }

__device__ inline f32x4 mfma16(bf16x8 a, bf16x8 b, f32x4 c) {
  return __builtin_amdgcn_mfma_f32_16x16x32_bf16(a, b, c, 0, 0, 0);
}

__device__ inline unsigned cvt_pk_bf16(float lo, float hi) {  // lo->[15:0], hi->[31:16]
  unsigned r;
  asm("v_cvt_pk_bf16_f32 %0, %1, %2" : "=v"(r) : "v"(lo), "v"(hi));
  return r;
}

__device__ inline f32x4 vmax4(f32x4 a, f32x4 b) {
  f32x4 r;
  r[0] = fmaxf(a[0], b[0]); r[1] = fmaxf(a[1], b[1]);
  r[2] = fmaxf(a[2], b[2]); r[3] = fmaxf(a[3], b[3]);
  return r;
}

// async global->LDS, 16B per lane; LDS dest = wave-uniform base + lane*16
__device__ inline void stage16(const void* g, void* l) {
  __builtin_amdgcn_global_load_lds((__attribute__((address_space(1))) void*)g,
                                   (__attribute__((address_space(3))) void*)l,
                                   16, 0, 0);
}

// Redistribute MFMA C-layout packed bf16 pairs into B-frag u32s.
__device__ inline void quad_repack(unsigned pkA, unsigned pkB, int quad,
                                   unsigned& mlo, unsigned& mhi) {
  unsigned y = (quad < 2) ? pkA : pkB;
  unsigned z = (quad < 2) ? pkB : pkA;
  unsigned a16 = (unsigned)__shfl_xor((int)y, 16);
  unsigned a32 = (unsigned)__shfl_xor((int)z, 32);
  unsigned a48 = (unsigned)__shfl_xor((int)z, 48);
  mlo = (quad == 0) ? y   : (quad == 1) ? a48 : (quad == 2) ? a32 : a16;
  mhi = (quad == 0) ? a16 : (quad == 1) ? a32 : (quad == 2) ? a48 : y;
}

// ---------------- weight fp32 -> bf16 conversion (float4) ----------------
// concatenated: qkv(98304) | proj(32768) | ff1(32768) | ff2(32768) | wout(3964928)
// all segment sizes are multiples of 4 -> no straddle. grid 4064 exact.
__global__ __launch_bounds__(256) void convw_kernel(
    const float* __restrict__ qkvw, const float* __restrict__ projw,
    const float* __restrict__ ff1w, const float* __restrict__ ff2w,
    const float* __restrict__ wout, u16* __restrict__ dst) {
  int i = (blockIdx.x * 256 + threadIdx.x) * 4;
  const float* src; int off;
  if (i < 98304) { src = qkvw; off = i; }
  else if (i < 131072) { src = projw; off = i - 98304; }
  else if (i < 163840) { src = ff1w; off = i - 131072; }
  else if (i < 196608) { src = ff2w; off = i - 163840; }
  else { src = wout; off = i - 196608; }
  float4 f = *(const float4*)(src + off);
  u32x2 o = { cvt_pk_bf16(f.x, f.y), cvt_pk_bf16(f.z, f.w) };
  *(u32x2*)(dst + i) = o;
}

// ---------------- input projection + tree PE + permutation ---------------
__global__ __launch_bounds__(256) void inproj_kernel(
    const float* __restrict__ forest, const int* __restrict__ adj,
    const int* __restrict__ perm, const float* __restrict__ WIN,
    const float* __restrict__ BIN, u16* __restrict__ X) {
  __shared__ float wf[128 * 12];
  __shared__ float fr[121 * 12];
  __shared__ float pe[121 * 12];
  __shared__ int pm[121];
  int s = blockIdx.x, tid = threadIdx.x;
  const float* fg = forest + (size_t)s * (NTOK * 12);
  const int* ag = adj + (size_t)s * (120 * 3);
  for (int i = tid; i < 128 * 12; i += 256) wf[i] = WIN[i];
  for (int i = tid; i < 121 * 12; i += 256) { fr[i] = fg[i]; pe[i] = 0.f; }
  if (tid < 121) pm[tid] = perm[tid];
  __syncthreads();
  if (tid > 0 && tid < 121) {
    int n = tid;
    int l = (n <= 3) ? 1 : (n <= 12) ? 2 : (n <= 39) ? 3 : 4;  // level by index range
    int cur = n;
    while (cur > 0) {  // walk to root, set bit (level-1)*3 + branch at each hop
      int par = ag[(cur - 1) * 3];
      int br = ag[(cur - 1) * 3 + 2];
      pe[n * 12 + (l - 1) * 3 + br] = 1.f;
      cur = par; l--;
    }
  }
  __syncthreads();
  int h = tid & 127;
  for (int base = 0; base < 121; base += 2) {
    int i = base + (tid >> 7);
    if (i < 121) {
      int node = pm[i];  // x_perm[:, i] = x[:, perm[i]]
      float v = BIN[h];
#pragma unroll
      for (int k = 0; k < 12; ++k) v += fr[node * 12 + k] * wf[h * 12 + k];
      if (h < 12) v += pe[node * 12 + h];  // PE only touches channels 0..11
      X[(size_t)s * (NTOK * HD) + i * HD + h] = f2bf(v);
    }
  }
}

// ---------------- barrier-free fused attention (swapped-operand, r9) -----
// Grid 4096: WG = (seq, head-pair). 4 waves; wave = (head slot hs = wave>>1,
// half = wave&1). Stage X_seq into swizzled LDS (global_load_lds), hoist
// W fragments to registers, then: K/V build -> barrier -> 4 query M-tiles
// (Q^T -> S^T -> in-register softmax -> O^T), unroll-2 pipelined.
// LDS: KV 32768B + X-stage 31744B = 64512B -> 2 WG/CU.
__global__ __launch_bounds__(256, 2) void attn_kernel(
    const u16* __restrict__ X, u16* __restrict__ O,
    const u16* __restrict__ WQKV, const float* __restrict__ QKVB, int layer) {
  __shared__ u16 lds[16384];   // K/V per head-slot
  __shared__ u16 xl[15872];    // staged X: 124 rows x 128, 16B-chunk c at slot c^(r&7)
  int tid = threadIdx.x;
  int wave = tid >> 6, lane = tid & 63, l16 = lane & 15, quad = lane >> 4;
  int seq = blockIdx.x >> 1;
  int head = ((blockIdx.x & 1) << 1) | (wave >> 1);
  int half = wave & 1;
  int hs = wave >> 1;
  u16* Kh = lds + hs * 4096;          // K[t][d]: t*32 + ((d>>3 ^ t&3)<<3) + (d&7)
  u16* Vh = lds + 8192 + hs * 4096;   // Vt[d][t]: d*128 + ((t>>3 ^ d&15)<<3) + (t&7)
  const u16* Xs = X + (size_t)seq * (NTOK * HD);
  const f32x4 fz = {0.f, 0.f, 0.f, 0.f};
  const int wbase = layer * 384 + head * 32;
  const u16* WQ = WQKV + (size_t)wbase * HD;
  const u16* WK = WQKV + (size_t)(wbase + 128) * HD;
  const u16* WV = WQKV + (size_t)(wbase + 256) * HD;

  // ---- phase 0: stage X (121 rows, clamped copies to 123) into LDS ----
  {
    const char* Xb = (const char*)Xs;
#pragma unroll
    for (int j = 0; j < 8; ++j) {
      int i = wave * 8 + j;
      if (i < 31) {
        int n = i * 64 + lane;          // 16B chunk index
        int r = n >> 4, c = n & 15;
        int rc = r > 120 ? 120 : r;     // clamp pad rows to valid data
        stage16(Xb + rc * 256 + ((c ^ (r & 7)) << 4), (void*)(xl + i * 512));
      }
    }
  }
  // hoisted weight fragments (loop-invariant; issued while stage in flight)
  bf16x8 wqf[2][4], wkf[2][4], wvf[2][4];
#pragma unroll
  for (int nt = 0; nt < 2; ++nt)
#pragma unroll
    for (int k = 0; k < 4; ++k) {
      size_t off = (size_t)(nt * 16 + l16) * HD + k * 32 + quad * 8;
      wqf[nt][k] = *(const bf16x8*)(WQ + off);
      wkf[nt][k] = *(const bf16x8*)(WK + off);
      wvf[nt][k] = *(const bf16x8*)(WV + off);
    }
  float kb2[2], vb2[2];
#pragma unroll
  for (int nt = 0; nt < 2; ++nt) {
    kb2[nt] = QKVB[wbase + 128 + nt * 16 + l16];
    vb2[nt] = QKVB[wbase + 256 + nt * 16 + l16];
  }
  const float scl = 0.17677669529663687f * 1.4426950408889634f;  // 1/sqrt(32)*log2(e)
  float qbias[2][4];  // Q bias for dim = nt*16 + quad*4 + r
#pragma unroll
  for (int nt = 0; nt < 2; ++nt)
#pragma unroll
    for (int r = 0; r < 4; ++r)
      qbias[nt][r] = QKVB[wbase + nt * 16 + quad * 4 + r];
  asm volatile("s_waitcnt vmcnt(0)" ::: "memory");
  __syncthreads();  // X staged (all waves)

  // ---- phase 1: K, V^T for tokens [half*64, half*64+64) of this head ----
  // unroll 2: two independent build chains interleave (ds_read/MFMA/pack)
#pragma unroll 2
  for (int mt = 0; mt < 4; ++mt) {
    int tb = half * 64 + mt * 16;
    int arow = tb + l16; if (arow > 120) arow = 120;  // pad rows: any valid data
    bf16x8 a[4];
#pragma unroll
    for (int k = 0; k < 4; ++k)
      a[k] = *(const bf16x8*)(xl + arow * 128 + (((k * 4 + quad) ^ (arow & 7)) << 3));
#pragma unroll
    for (int nt = 0; nt < 2; ++nt) {
      f32x4 kacc = fz, vacc = fz;
      __builtin_amdgcn_s_setprio(1);
#pragma unroll
      for (int k = 0; k < 4; ++k) {
        kacc = mfma16(a[k], wkf[nt][k], kacc);
        vacc = mfma16(a[k], wvf[nt][k], vacc);
      }
      __builtin_amdgcn_s_setprio(0);
      int d = nt * 16 + l16;
      int kc = nt * 2 + (l16 >> 3);  // d>>3
#pragma unroll
      for (int r = 0; r < 4; ++r) {
        int t = tb + quad * 4 + r;
        Kh[t * 32 + ((kc ^ (t & 3)) << 3) + (l16 & 7)] = f2bf(kacc[r] + kb2[nt]);
      }
      float vv[4];
#pragma unroll
      for (int r = 0; r < 4; ++r) {
        int t = tb + quad * 4 + r;
        vv[r] = (t < NTOK) ? (vacc[r] + vb2[nt]) : 0.f;  // zero pad rows
      }
      // t>>3 and the swizzle slot are r-invariant: 4 consecutive u16 -> one b64
      u32x2 vp = { cvt_pk_bf16(vv[0], vv[1]), cvt_pk_bf16(vv[2], vv[3]) };
      *(u32x2*)(Vh + d * 128 + ((((tb >> 3) + (quad >> 1)) ^ l16) << 3) + (quad & 1) * 4) = vp;
    }
  }
  __syncthreads();  // K/V halves built by both waves of the head

  // ---- phase 2: 4 query M-tiles per wave, swapped operands ----
  // unroll 2: tiles fully independent -> softmax VALU of one tile hides
  // under the other tile's MFMA/ds_read latency (T15-style, via ILP).
#pragma unroll 2
  for (int qmt = 0; qmt < 4; ++qmt) {
    int qb = (half * 4 + qmt) * 16;
    int qrow = qb + l16;
    int qrowc = qrow > 120 ? 120 : qrow;
    // B-frag of X query rows from staged LDS: lane = q-token column
    bf16x8 xb[4];
#pragma unroll
    for (int k = 0; k < 4; ++k)
      xb[k] = *(const bf16x8*)(xl + qrowc * 128 + (((k * 4 + quad) ^ (qrowc & 7)) << 3));
    // Q^T = WQ @ X^T: C col = q (l16), row = dim (nt*16 + quad*4 + r)
    f32x4 qv[2];
    __builtin_amdgcn_s_setprio(1);
#pragma unroll
    for (int nt = 0; nt < 2; ++nt) {
      f32x4 acc = fz;
#pragma unroll
      for (int k = 0; k < 4; ++k) acc = mfma16(wqf[nt][k], xb[k], acc);
      qv[nt] = acc;
    }
    __builtin_amdgcn_s_setprio(0);
    // pack Q to bf16 pairs and repack C-layout -> B-frag (lane=q, elems=dims)
    unsigned qpk[2][2];
#pragma unroll
    for (int nt = 0; nt < 2; ++nt)
#pragma unroll
      for (int r2 = 0; r2 < 2; ++r2)
        qpk[nt][r2] = cvt_pk_bf16((qv[nt][2 * r2] + qbias[nt][2 * r2]) * scl,
                                  (qv[nt][2 * r2 + 1] + qbias[nt][2 * r2 + 1]) * scl);
    u32x4 qu;
#pragma unroll
    for (int r2 = 0; r2 < 2; ++r2) {
      unsigned mlo, mhi;
      quad_repack(qpk[0][r2], qpk[1][r2], quad, mlo, mhi);
      qu[r2] = mlo; qu[2 + r2] = mhi;
    }
    bf16x8 qfrag = __builtin_bit_cast(bf16x8, qu);
    // S^T: rows = k-token (nt*16 + quad*4 + r), cols = q (l16)
    f32x4 lg[8];
    __builtin_amdgcn_s_setprio(1);
#pragma unroll
    for (int nt = 0; nt < 8; ++nt) {
      bf16x8 ka = *(const bf16x8*)(Kh + (nt * 16 + l16) * 32 + ((quad ^ (l16 & 3)) << 3));
      lg[nt] = mfma16(ka, qfrag, fz);
    }
    __builtin_amdgcn_s_setprio(0);
    // in-register softmax: per-lane 32 k-values + 2 cross-quad shuffles.
    // K rows 121..127 are clamped copies of row 120 -> max unchanged; their
    // exp terms are zeroed below (exact mask).
    f32x4 t0 = vmax4(vmax4(lg[0], lg[1]), vmax4(lg[2], lg[3]));
    f32x4 t1 = vmax4(vmax4(lg[4], lg[5]), vmax4(lg[6], lg[7]));
    f32x4 tm = vmax4(t0, t1);
    float mx = fmaxf(fmaxf(tm[0], tm[1]), fmaxf(tm[2], tm[3]));
    mx = fmaxf(mx, __shfl_xor(mx, 16));
    mx = fmaxf(mx, __shfl_xor(mx, 32));
#pragma unroll
    for (int nt = 0; nt < 8; ++nt)
#pragma unroll
      for (int r = 0; r < 4; ++r) {
        float ev = __builtin_amdgcn_exp2f(lg[nt][r] - mx);  // exp2-domain
        if (nt == 7 && (quad * 4 + r > 8)) ev = 0.f;        // k = 112+quad*4+r > 120
        lg[nt][r] = ev;
      }
    f32x4 s4 = (lg[0] + lg[1]) + (lg[2] + lg[3]) + ((lg[4] + lg[5]) + (lg[6] + lg[7]));
    float sum = (s4[0] + s4[1]) + (s4[2] + s4[3]);
    sum += __shfl_xor(sum, 16);
    sum += __shfl_xor(sum, 32);
    float rinv = __builtin_amdgcn_rcpf(sum);  // normalize deferred to O epilogue
    // P -> bf16 pairs: pk[nt][r2] = tokens (nt*16 + quad*4 + 2r2, +1)
    unsigned pk[8][2];
#pragma unroll
    for (int nt = 0; nt < 8; ++nt)
#pragma unroll
      for (int r2 = 0; r2 < 2; ++r2)
        pk[nt][r2] = cvt_pk_bf16(lg[nt][2 * r2], lg[nt][2 * r2 + 1]);
    // O^T = V^T @ P: per 32-token k-step, repack P to B-frag and MFMA
    f32x4 oacc[2] = {fz, fz};
#pragma unroll
    for (int s = 0; s < 4; ++s) {
      u32x4 pu;
#pragma unroll
      for (int r2 = 0; r2 < 2; ++r2) {
        unsigned mlo, mhi;
        quad_repack(pk[2 * s][r2], pk[2 * s + 1][r2], quad, mlo, mhi);
        pu[r2] = mlo; pu[2 + r2] = mhi;
      }
      bf16x8 pfrag = __builtin_bit_cast(bf16x8, pu);
      __builtin_amdgcn_s_setprio(1);
#pragma unroll
      for (int mt = 0; mt < 2; ++mt) {
        bf16x8 va = *(const bf16x8*)(Vh + (mt * 16 + l16) * 128 + (((s * 4 + quad) ^ l16) << 3));
        oacc[mt] = mfma16(va, pfrag, oacc[mt]);
      }
      __builtin_amdgcn_s_setprio(0);
    }
    // epilogue: C col = q (l16), row = dim (mt*16 + quad*4 + r); pack dim-pairs
    if (qrow < NTOK) {
      u16* Op = O + (size_t)seq * (NTOK * HD) + (size_t)qrow * HD + head * 32;
#pragma unroll
      for (int mt = 0; mt < 2; ++mt) {
        u32x2 w = { cvt_pk_bf16(oacc[mt][0] * rinv, oacc[mt][1] * rinv),
                    cvt_pk_bf16(oacc[mt][2] * rinv, oacc[mt][3] * rinv) };
        *(u32x2*)(Op + mt * 16 + quad * 4) = w;
      }
    }
  }
}

// ---------------- fused proj+LN1+ff1+ff2+LN2, channel-partitioned ---------
// Block = 64 token-rows (3872 blocks exact). Wave w owns out-channels
// [32w,32w+32) for proj, ff1, ff2: 24 weight frags hoisted once, loaded
// under the stage wait. Each wave covers all 64 tokens (4 groups of 16).
// LN via 2KB partial-sum LDS. LDS 34816B -> 3 WG/CU (bounds(256,3);
// 4 WG/CU would cap VGPR at 128 -> spill, r10 lesson). 5 barriers.
__global__ __launch_bounds__(256, 3) void blockln_kernel(
    u16* __restrict__ X, const u16* __restrict__ O,
    const u16* __restrict__ WP, const float* __restrict__ PB,
    const u16* __restrict__ W1, const float* __restrict__ B1,
    const u16* __restrict__ W2, const float* __restrict__ B2,
    const float* __restrict__ G1, const float* __restrict__ Bt1,
    const float* __restrict__ G2, const float* __restrict__ Bt2, int layer) {
  __shared__ u16 as_[64 * 128];    // staged O -> LN1 output
  __shared__ u16 xr[64 * 128];     // staged X residual -> relu(ff1)
  __shared__ float part[512];      // per-(token, wave) LN partials (sum, ssq)
  int r0 = blockIdx.x * 64, tid = threadIdx.x;
  int wave = tid >> 6, lane = tid & 63, l16 = lane & 15, quad = lane >> 4;
  const f32x4 fz = {0.f, 0.f, 0.f, 0.f};
  const int Lb = layer * 128;
  const int ch0 = wave * 32;          // this wave's output channels
  const int ch8b = wave * 4 + (quad >> 1);  // 16B-chunk base for (wave, quad)

  // ---- stage O and X (16B chunk c of row r at slot c^(r&7)) ----
  {
    const char* Ob = (const char*)(O + (size_t)r0 * HD);
    const char* Xb = (const char*)(X + (size_t)r0 * HD);
#pragma unroll
    for (int j = 0; j < 4; ++j) {
      int n = wave * 256 + j * 64 + lane;  // 16B chunk index (1024 per buffer)
      int r = n >> 4, c = n & 15;
      int gsrc = r * 256 + ((c ^ (r & 7)) << 4);
      stage16(Ob + gsrc, (void*)(as_ + (wave * 256 + j * 64) * 8));
      stage16(Xb + gsrc, (void*)(xr + (wave * 256 + j * 64) * 8));
    }
  }
  // hoist this wave's weight frags for all 3 GEMMs (latency hides under stage)
  bf16x8 wpf[2][4], w1f[2][4], w2f[2][4];
#pragma unroll
  for (int g = 0; g < 2; ++g)
#pragma unroll
    for (int k = 0; k < 4; ++k) {
      size_t off = (size_t)(Lb + ch0 + g * 16 + l16) * HD + k * 32 + quad * 8;
      wpf[g][k] = *(const bf16x8*)(WP + off);
      w1f[g][k] = *(const bf16x8*)(W1 + off);
      w2f[g][k] = *(const bf16x8*)(W2 + off);
    }
  asm volatile("s_waitcnt vmcnt(0)" ::: "memory");
  __syncthreads();  // B1: staged

  // ---- proj (+PB, +X residual) over all 4 token groups; LN1 partials ----
  f32x4 acc[2][4];
#pragma unroll
  for (int mt = 0; mt < 4; ++mt) {
    int tok = mt * 16 + l16;
    bf16x8 of[4];
#pragma unroll
    for (int k = 0; k < 4; ++k)
      of[k] = *(const bf16x8*)(as_ + tok * 128 + (((k * 4 + quad) ^ (tok & 7)) << 3));
    __builtin_amdgcn_s_setprio(1);
#pragma unroll
    for (int g = 0; g < 2; ++g) {
      f32x4 a = fz;
#pragma unroll
      for (int k = 0; k < 4; ++k) a = mfma16(wpf[g][k], of[k], a);
      acc[g][mt] = a;
    }
    __builtin_amdgcn_s_setprio(0);
    float sum = 0.f, ssq = 0.f;
#pragma unroll
    for (int g = 0; g < 2; ++g) {
      float4 pb4 = *(const float4*)(PB + Lb + ch0 + g * 16 + quad * 4);
      int sl = (ch8b + g * 2) ^ (tok & 7);
      u32x2 xw = *(const u32x2*)(xr + tok * 128 + (sl << 3) + (quad & 1) * 4);
      acc[g][mt][0] += pb4.x + bfu32lo(xw[0]);
      acc[g][mt][1] += pb4.y + bfu32hi(xw[0]);
      acc[g][mt][2] += pb4.z + bfu32lo(xw[1]);
      acc[g][mt][3] += pb4.w + bfu32hi(xw[1]);
#pragma unroll
      for (int r = 0; r < 4; ++r) { sum += acc[g][mt][r]; ssq += acc[g][mt][r] * acc[g][mt][r]; }
    }
    sum += __shfl_xor(sum, 16); ssq += __shfl_xor(ssq, 16);
    sum += __shfl_xor(sum, 32); ssq += __shfl_xor(ssq, 32);
    if (quad == 0) *(float2*)(part + ((mt * 4 + wave) * 16 + l16) * 2) = make_float2(sum, ssq);
  }
  __syncthreads();  // B2: LN1 partials visible

  // ---- LN1 apply -> as_ (overwrites O stage; same swizzle) ----
#pragma unroll
  for (int mt = 0; mt < 4; ++mt) {
    int tok = mt * 16 + l16;
    float sum = 0.f, ssq = 0.f;
#pragma unroll
    for (int ww = 0; ww < 4; ++ww) {
      float2 p = *(const float2*)(part + ((mt * 4 + ww) * 16 + l16) * 2);
      sum += p.x; ssq += p.y;
    }
    float mean = sum * (1.f / 128.f);
    float rstd = rsqrtf(ssq * (1.f / 128.f) - mean * mean + EPSF);
#pragma unroll
    for (int g = 0; g < 2; ++g) {
      float4 g4 = *(const float4*)(G1 + Lb + ch0 + g * 16 + quad * 4);
      float4 b4 = *(const float4*)(Bt1 + Lb + ch0 + g * 16 + quad * 4);
      u32x2 wv = { cvt_pk_bf16((acc[g][mt][0] - mean) * rstd * g4.x + b4.x,
                               (acc[g][mt][1] - mean) * rstd * g4.y + b4.y),
                   cvt_pk_bf16((acc[g][mt][2] - mean) * rstd * g4.z + b4.z,
                               (acc[g][mt][3] - mean) * rstd * g4.w + b4.w) };
      int sl = (ch8b + g * 2) ^ (tok & 7);
      *(u32x2*)(as_ + tok * 128 + (sl << 3) + (quad & 1) * 4) = wv;
    }
  }
  __syncthreads();  // B3: LN1 out complete

  // ---- ff1 + relu(+B1) -> xr (overwrites X stage) ----
#pragma unroll
  for (int mt = 0; mt < 4; ++mt) {
    int tok = mt * 16 + l16;
    bf16x8 af[4];
#pragma unroll
    for (int k = 0; k < 4; ++k)
      af[k] = *(const bf16x8*)(as_ + tok * 128 + (((k * 4 + quad) ^ (tok & 7)) << 3));
    __builtin_amdgcn_s_setprio(1);
#pragma unroll
    for (int g = 0; g < 2; ++g) {
      f32x4 a = fz;
#pragma unroll
      for (int k = 0; k < 4; ++k) a = mfma16(w1f[g][k], af[k], a);
      float4 b14 = *(const float4*)(B1 + Lb + ch0 + g * 16 + quad * 4);
      u32x2 wv = { cvt_pk_bf16(fmaxf(a[0] + b14.x, 0.f), fmaxf(a[1] + b14.y, 0.f)),
                   cvt_pk_bf16(fmaxf(a[2] + b14.z, 0.f), fmaxf(a[3] + b14.w, 0.f)) };
      int sl = (ch8b + g * 2) ^ (tok & 7);
      *(u32x2*)(xr + tok * 128 + (sl << 3) + (quad & 1) * 4) = wv;
    }
    __builtin_amdgcn_s_setprio(0);
  }
  __syncthreads();  // B4: H complete

  // ---- ff2 (+B2, +LN1out residual); LN2 partials ----
#pragma unroll
  for (int mt = 0; mt < 4; ++mt) {
    int tok = mt * 16 + l16;
    bf16x8 hf[4];
#pragma unroll
    for (int k = 0; k < 4; ++k)
      hf[k] = *(const bf16x8*)(xr + tok * 128 + (((k * 4 + quad) ^ (tok & 7)) << 3));
    __builtin_amdgcn_s_setprio(1);
#pragma unroll
    for (int g = 0; g < 2; ++g) {
      f32x4 a = fz;
#pragma unroll
      for (int k = 0; k < 4; ++k) a = mfma16(w2f[g][k], hf[k], a);
      acc[g][mt] = a;
    }
    __builtin_amdgcn_s_setprio(0);
    float sum = 0.f, ssq = 0.f;
#pragma unroll
    for (int g = 0; g < 2; ++g) {
      float4 b24 = *(const float4*)(B2 + Lb + ch0 + g * 16 + quad * 4);
      int sl = (ch8b + g * 2) ^ (tok & 7);
      u32x2 lw = *(const u32x2*)(as_ + tok * 128 + (sl << 3) + (quad & 1) * 4);
      acc[g][mt][0] += b24.x + bfu32lo(lw[0]);
      acc[g][mt][1] += b24.y + bfu32hi(lw[0]);
      acc[g][mt][2] += b24.z + bfu32lo(lw[1]);
      acc[g][mt][3] += b24.w + bfu32hi(lw[1]);
#pragma unroll
      for (int r = 0; r < 4; ++r) { sum += acc[g][mt][r]; ssq += acc[g][mt][r] * acc[g][mt][r]; }
    }
    sum += __shfl_xor(sum, 16); ssq += __shfl_xor(ssq, 16);
    sum += __shfl_xor(sum, 32); ssq += __shfl_xor(ssq, 32);
    if (quad == 0) *(float2*)(part + ((mt * 4 + wave) * 16 + l16) * 2) = make_float2(sum, ssq);
  }
  __syncthreads();  // B5: LN2 partials visible

  // ---- LN2 apply -> X (b64 global stores) ----
#pragma unroll
  for (int mt = 0; mt < 4; ++mt) {
    int tok = mt * 16 + l16;
    float sum = 0.f, ssq = 0.f;
#pragma unroll
    for (int ww = 0; ww < 4; ++ww) {
      float2 p = *(const float2*)(part + ((mt * 4 + ww) * 16 + l16) * 2);
      sum += p.x; ssq += p.y;
    }
    float mean = sum * (1.f / 128.f);
    float rstd = rsqrtf(ssq * (1.f / 128.f) - mean * mean + EPSF);
    u16* Xp = X + (size_t)(r0 + tok) * HD + ch0;
#pragma unroll
    for (int g = 0; g < 2; ++g) {
      float4 g4 = *(const float4*)(G2 + Lb + ch0 + g * 16 + quad * 4);
      float4 b4 = *(const float4*)(Bt2 + Lb + ch0 + g * 16 + quad * 4);
      u32x2 wv = { cvt_pk_bf16((acc[g][mt][0] - mean) * rstd * g4.x + b4.x,
                               (acc[g][mt][1] - mean) * rstd * g4.y + b4.y),
                   cvt_pk_bf16((acc[g][mt][2] - mean) * rstd * g4.z + b4.z,
                               (acc[g][mt][3] - mean) * rstd * g4.w + b4.w) };
      *(u32x2*)(Xp + g * 16 + quad * 4) = wv;
    }
  }
}

// ---------------- final GEMM (M=2048,K=15488,N=256), split-K=16 ----------
// 512 1D blocks, XCD-chunked: swz=(bid&7)*64+(bid>>3) -> XCD k owns the
// contiguous work range [64k,64k+64) = all 32 m-tiles of j in {2k,2k+1}.
__global__ __launch_bounds__(256, 2) void outgemm_kernel(
    const u16* __restrict__ X, const u16* __restrict__ WO, float* __restrict__ PART) {
  __shared__ u16 as_[64 * 136];
  int bid = blockIdx.x;
  int swz = (bid & 7) * 64 + (bid >> 3);   // bijective: 512 = 8 * 64
  int mtile = swz & 31, j = swz >> 5;
  int tid = threadIdx.x, wave = tid >> 6, lane = tid & 63, l16 = lane & 15, quad = lane >> 4;
  int s0 = mtile * 64;
  int k0 = (j * 484) / 16, k1 = ((j + 1) * 484) / 16;  // k-steps of 32 over K=15488
  const f32x4 fz = {0.f, 0.f, 0.f, 0.f};
  f32x4 acc[4][4];
  for (int a = 0; a < 4; ++a) for (int b = 0; b < 4; ++b) acc[a][b] = fz;
  for (int kb = k0; kb < k1; kb += 4) {
    int nst = (k1 - kb < 4) ? (k1 - kb) : 4;
    __syncthreads();
    int chunks = 64 * 4 * nst;
    for (int c = tid; c < chunks; c += 256) {
      int row = c / (4 * nst), g = c % (4 * nst);
      *(uint4*)(as_ + row * 136 + g * 8) =
          *(const uint4*)(X + (size_t)(s0 + row) * 15488 + kb * 32 + g * 8);
    }
    __syncthreads();
    for (int kk = 0; kk < nst; ++kk) {
      bf16x8 af[4];
#pragma unroll
      for (int mt = 0; mt < 4; ++mt)
        af[mt] = *(const bf16x8*)(as_ + (mt * 16 + l16) * 136 + kk * 32 + quad * 8);
#pragma unroll
      for (int n = 0; n < 4; ++n) {
        int nt = wave * 4 + n;
        bf16x8 bf = *(const bf16x8*)(WO + (size_t)(nt * 16 + l16) * 15488 +
                                     (size_t)(kb + kk) * 32 + quad * 8);
#pragma unroll
        for (int mt = 0; mt < 4; ++mt) acc[mt][n] = mfma16(af[mt], bf, acc[mt][n]);
      }
    }
  }
  for (int mt = 0; mt < 4; ++mt)
    for (int n = 0; n < 4; ++n) {
      int nt = wave * 4 + n;
#pragma unroll
      for (int r = 0; r < 4; ++r) {
        int row = s0 + mt * 16 + quad * 4 + r;
        PART[((size_t)j * 2048 + row) * 256 + nt * 16 + l16] = acc[mt][n][r];
      }
    }
}

// ---------------- reduce split-K partials + bias + final LN --------------
__global__ __launch_bounds__(256) void lnf_kernel(
    const float* __restrict__ PART, const float* __restrict__ BO,
    const float* __restrict__ G, const float* __restrict__ Bt, float* __restrict__ OUT) {
  int s = blockIdx.x * 4 + (threadIdx.x >> 6);  // one wave per sequence
  int lane = threadIdx.x & 63;
  float v[4], sum = 0.f, ssq = 0.f;
#pragma unroll
  for (int i = 0; i < 4; ++i) {
    int c = lane + i * 64;
    float t = BO[c];
    for (int jj = 0; jj < 16; ++jj) t += PART[((size_t)jj * 2048 + s) * 256 + c];
    v[i] = t; sum += t; ssq += t * t;
  }
  for (int m = 1; m <= 32; m <<= 1) { sum += __shfl_xor(sum, m, 64); ssq += __shfl_xor(ssq, m, 64); }
  float mean = sum * (1.f / 256.f);
  float var = ssq * (1.f / 256.f) - mean * mean;
  float rstd = rsqrtf(var + EPSF);
#pragma unroll
  for (int i = 0; i < 4; ++i) {
    int c = lane + i * 64;
    OUT[(size_t)s * 256 + c] = (v[i] - mean) * rstd * G[c] + Bt[c];
  }
}

extern "C" void kernel_launch(void* const* d_in, const int* in_sizes, int n_in,
                              void* d_out, int out_size, void* d_ws, size_t ws_size,
                              hipStream_t stream) {
  const float* forest = (const float*)d_in[0];
  const int* adj      = (const int*)d_in[1];
  const int* perm     = (const int*)d_in[2];
  const float* w_in   = (const float*)d_in[3];
  const float* b_in   = (const float*)d_in[4];
  const float* qkv_w  = (const float*)d_in[5];
  const float* qkv_b  = (const float*)d_in[6];
  const float* proj_w = (const float*)d_in[7];
  const float* proj_b = (const float*)d_in[8];
  const float* ff1_w  = (const float*)d_in[9];
  const float* ff1_b  = (const float*)d_in[10];
  const float* ff2_w  = (const float*)d_in[11];
  const float* ff2_b  = (const float*)d_in[12];
  const float* ln1_g  = (const float*)d_in[13];
  const float* ln1_b  = (const float*)d_in[14];
  const float* ln2_g  = (const float*)d_in[15];
  const float* ln2_b  = (const float*)d_in[16];
  const float* w_out  = (const float*)d_in[17];
  const float* b_out  = (const float*)d_in[18];
  const float* lnf_g  = (const float*)d_in[19];
  const float* lnf_b  = (const float*)d_in[20];

  // workspace map (bytes): bf16 weights 8,323,072 | X 63,438,848 | O 63,438,848 | PART 33,554,432
  char* ws = (char*)d_ws;
  u16* WB = (u16*)ws;
  u16* X  = (u16*)(ws + 8323072);
  u16* O  = (u16*)(ws + 8323072 + 63438848);
  float* PART = (float*)(ws + 8323072 + 2 * (size_t)63438848);

  u16* WQKV  = WB;
  u16* WPROJ = WB + 98304;
  u16* WFF1  = WB + 131072;
  u16* WFF2  = WB + 163840;
  u16* WOUT  = WB + 196608;

  convw_kernel<<<4064, 256, 0, stream>>>(qkv_w, proj_w, ff1_w, ff2_w, w_out, WB);
  inproj_kernel<<<2048, 256, 0, stream>>>(forest, adj, perm, w_in, b_in, X);
  for (int layer = 0; layer < 2; ++layer) {
    attn_kernel<<<4096, 256, 0, stream>>>(X, O, WQKV, qkv_b, layer);
    blockln_kernel<<<3872, 256, 0, stream>>>(X, O, WPROJ, proj_b, WFF1, ff1_b,
                                             WFF2, ff2_b, ln1_g, ln1_b, ln2_g, ln2_b, layer);
  }
  outgemm_kernel<<<512, 256, 0, stream>>>(X, WOUT, PART);
  lnf_kernel<<<512, 256, 0, stream>>>(PART, b_out, lnf_g, lnf_b, (float*)d_out);
}

// Round 14
// 581.220 us; speedup vs baseline: 1.0415x; 1.0415x over previous
//
#include <hip/hip_runtime.h>

// TreeTransformer on MI355X: bf16 MFMA pipeline.
// B=32,A=64 -> S=2048 sequences, N=121 tokens, H=128, heads=4(hd=32), NL=2, OUT=256.
// r1-r6: swapped-operand attn + fused blockln (channel-partitioned).  [594us]
// r7/r8/r10/r12: occupancy experiments ALL REGRESSED (dup fetch / write frag
//      / spill / per-block fixed-cost dilution). 2 WG/CU is the local optimum.
// r9: qmt/mt unroll-2 ILP. attn 114.5us.
// r11: outgemm XCD-swizzled, convw float4.  [581us <- best]
// r13: blockln reverted to r11 (128-token). Single variable: attn phase-2
//      fully unrolled (4 q-tiles visible) -> deeper cross-tile ILP; VGPR
//      headroom huge (88/256 at 2 waves/SIMD), the only lever with a
//      positive track record here (r9 +5%).

typedef unsigned short u16;
typedef __attribute__((ext_vector_type(8))) short bf16x8;  // 8 bf16 (4 VGPRs)
typedef __attribute__((ext_vector_type(4))) float f32x4;
typedef __attribute__((ext_vector_type(4))) unsigned int u32x4;
typedef __attribute__((ext_vector_type(2))) unsigned int u32x2;

#define NTOK 121
#define HD 128
#define S_TOT 2048
#define EPSF 1e-5f

__device__ inline u16 f2bf(float f) {  // round-to-nearest-even fp32->bf16
  unsigned u = __float_as_uint(f);
  return (u16)((u + 0x7FFFu + ((u >> 16) & 1u)) >> 16);
}
__device__ inline float bf2f(u16 h) { return __uint_as_float(((unsigned)h) << 16); }
__device__ inline float bfu32lo(unsigned u) { return __uint_as_float(u << 16); }
__device__ inline float bfu32hi(unsigned u) { return __uint_as_float(u & 0xffff0000u); }

__device__ inline f32x4 mfma16(bf16x8 a, bf16x8 b, f32x4 c) {
  return __builtin_amdgcn_mfma_f32_16x16x32_bf16(a, b, c, 0, 0, 0);
}

__device__ inline unsigned cvt_pk_bf16(float lo, float hi) {  // lo->[15:0], hi->[31:16]
  unsigned r;
  asm("v_cvt_pk_bf16_f32 %0, %1, %2" : "=v"(r) : "v"(lo), "v"(hi));
  return r;
}

__device__ inline f32x4 vmax4(f32x4 a, f32x4 b) {
  f32x4 r;
  r[0] = fmaxf(a[0], b[0]); r[1] = fmaxf(a[1], b[1]);
  r[2] = fmaxf(a[2], b[2]); r[3] = fmaxf(a[3], b[3]);
  return r;
}

// async global->LDS, 16B per lane; LDS dest = wave-uniform base + lane*16
__device__ inline void stage16(const void* g, void* l) {
  __builtin_amdgcn_global_load_lds((__attribute__((address_space(1))) void*)g,
                                   (__attribute__((address_space(3))) void*)l,
                                   16, 0, 0);
}

// Redistribute MFMA C-layout packed bf16 pairs into B-frag u32s.
__device__ inline void quad_repack(unsigned pkA, unsigned pkB, int quad,
                                   unsigned& mlo, unsigned& mhi) {
  unsigned y = (quad < 2) ? pkA : pkB;
  unsigned z = (quad < 2) ? pkB : pkA;
  unsigned a16 = (unsigned)__shfl_xor((int)y, 16);
  unsigned a32 = (unsigned)__shfl_xor((int)z, 32);
  unsigned a48 = (unsigned)__shfl_xor((int)z, 48);
  mlo = (quad == 0) ? y   : (quad == 1) ? a48 : (quad == 2) ? a32 : a16;
  mhi = (quad == 0) ? a16 : (quad == 1) ? a32 : (quad == 2) ? a48 : y;
}

// ---------------- weight fp32 -> bf16 conversion (float4) ----------------
// concatenated: qkv(98304) | proj(32768) | ff1(32768) | ff2(32768) | wout(3964928)
// all segment sizes are multiples of 4 -> no straddle. grid 4064 exact.
__global__ __launch_bounds__(256) void convw_kernel(
    const float* __restrict__ qkvw, const float* __restrict__ projw,
    const float* __restrict__ ff1w, const float* __restrict__ ff2w,
    const float* __restrict__ wout, u16* __restrict__ dst) {
  int i = (blockIdx.x * 256 + threadIdx.x) * 4;
  const float* src; int off;
  if (i < 98304) { src = qkvw; off = i; }
  else if (i < 131072) { src = projw; off = i - 98304; }
  else if (i < 163840) { src = ff1w; off = i - 131072; }
  else if (i < 196608) { src = ff2w; off = i - 163840; }
  else { src = wout; off = i - 196608; }
  float4 f = *(const float4*)(src + off);
  u32x2 o = { cvt_pk_bf16(f.x, f.y), cvt_pk_bf16(f.z, f.w) };
  *(u32x2*)(dst + i) = o;
}

// ---------------- input projection + tree PE + permutation ---------------
__global__ __launch_bounds__(256) void inproj_kernel(
    const float* __restrict__ forest, const int* __restrict__ adj,
    const int* __restrict__ perm, const float* __restrict__ WIN,
    const float* __restrict__ BIN, u16* __restrict__ X) {
  __shared__ float wf[128 * 12];
  __shared__ float fr[121 * 12];
  __shared__ float pe[121 * 12];
  __shared__ int pm[121];
  int s = blockIdx.x, tid = threadIdx.x;
  const float* fg = forest + (size_t)s * (NTOK * 12);
  const int* ag = adj + (size_t)s * (120 * 3);
  for (int i = tid; i < 128 * 12; i += 256) wf[i] = WIN[i];
  for (int i = tid; i < 121 * 12; i += 256) { fr[i] = fg[i]; pe[i] = 0.f; }
  if (tid < 121) pm[tid] = perm[tid];
  __syncthreads();
  if (tid > 0 && tid < 121) {
    int n = tid;
    int l = (n <= 3) ? 1 : (n <= 12) ? 2 : (n <= 39) ? 3 : 4;  // level by index range
    int cur = n;
    while (cur > 0) {  // walk to root, set bit (level-1)*3 + branch at each hop
      int par = ag[(cur - 1) * 3];
      int br = ag[(cur - 1) * 3 + 2];
      pe[n * 12 + (l - 1) * 3 + br] = 1.f;
      cur = par; l--;
    }
  }
  __syncthreads();
  int h = tid & 127;
  for (int base = 0; base < 121; base += 2) {
    int i = base + (tid >> 7);
    if (i < 121) {
      int node = pm[i];  // x_perm[:, i] = x[:, perm[i]]
      float v = BIN[h];
#pragma unroll
      for (int k = 0; k < 12; ++k) v += fr[node * 12 + k] * wf[h * 12 + k];
      if (h < 12) v += pe[node * 12 + h];  // PE only touches channels 0..11
      X[(size_t)s * (NTOK * HD) + i * HD + h] = f2bf(v);
    }
  }
}

// ---------------- barrier-free fused attention (swapped-operand) ---------
// Grid 4096: WG = (seq, head-pair). 4 waves; wave = (head slot hs = wave>>1,
// half = wave&1). Stage X_seq into swizzled LDS (global_load_lds), hoist
// W fragments to registers, then: K/V build -> barrier -> 4 query M-tiles
// (Q^T -> S^T -> in-register softmax -> O^T). Phase 2 fully unrolled for
// deep cross-tile ILP (r13). LDS 64512B -> 2 WG/CU.
__global__ __launch_bounds__(256, 2) void attn_kernel(
    const u16* __restrict__ X, u16* __restrict__ O,
    const u16* __restrict__ WQKV, const float* __restrict__ QKVB, int layer) {
  __shared__ u16 lds[16384];   // K/V per head-slot
  __shared__ u16 xl[15872];    // staged X: 124 rows x 128, 16B-chunk c at slot c^(r&7)
  int tid = threadIdx.x;
  int wave = tid >> 6, lane = tid & 63, l16 = lane & 15, quad = lane >> 4;
  int seq = blockIdx.x >> 1;
  int head = ((blockIdx.x & 1) << 1) | (wave >> 1);
  int half = wave & 1;
  int hs = wave >> 1;
  u16* Kh = lds + hs * 4096;          // K[t][d]: t*32 + ((d>>3 ^ t&3)<<3) + (d&7)
  u16* Vh = lds + 8192 + hs * 4096;   // Vt[d][t]: d*128 + ((t>>3 ^ d&15)<<3) + (t&7)
  const u16* Xs = X + (size_t)seq * (NTOK * HD);
  const f32x4 fz = {0.f, 0.f, 0.f, 0.f};
  const int wbase = layer * 384 + head * 32;
  const u16* WQ = WQKV + (size_t)wbase * HD;
  const u16* WK = WQKV + (size_t)(wbase + 128) * HD;
  const u16* WV = WQKV + (size_t)(wbase + 256) * HD;

  // ---- phase 0: stage X (121 rows, clamped copies to 123) into LDS ----
  {
    const char* Xb = (const char*)Xs;
#pragma unroll
    for (int j = 0; j < 8; ++j) {
      int i = wave * 8 + j;
      if (i < 31) {
        int n = i * 64 + lane;          // 16B chunk index
        int r = n >> 4, c = n & 15;
        int rc = r > 120 ? 120 : r;     // clamp pad rows to valid data
        stage16(Xb + rc * 256 + ((c ^ (r & 7)) << 4), (void*)(xl + i * 512));
      }
    }
  }
  // hoisted weight fragments (loop-invariant; issued while stage in flight)
  bf16x8 wqf[2][4], wkf[2][4], wvf[2][4];
#pragma unroll
  for (int nt = 0; nt < 2; ++nt)
#pragma unroll
    for (int k = 0; k < 4; ++k) {
      size_t off = (size_t)(nt * 16 + l16) * HD + k * 32 + quad * 8;
      wqf[nt][k] = *(const bf16x8*)(WQ + off);
      wkf[nt][k] = *(const bf16x8*)(WK + off);
      wvf[nt][k] = *(const bf16x8*)(WV + off);
    }
  float kb2[2], vb2[2];
#pragma unroll
  for (int nt = 0; nt < 2; ++nt) {
    kb2[nt] = QKVB[wbase + 128 + nt * 16 + l16];
    vb2[nt] = QKVB[wbase + 256 + nt * 16 + l16];
  }
  const float scl = 0.17677669529663687f * 1.4426950408889634f;  // 1/sqrt(32)*log2(e)
  float qbias[2][4];  // Q bias for dim = nt*16 + quad*4 + r
#pragma unroll
  for (int nt = 0; nt < 2; ++nt)
#pragma unroll
    for (int r = 0; r < 4; ++r)
      qbias[nt][r] = QKVB[wbase + nt * 16 + quad * 4 + r];
  asm volatile("s_waitcnt vmcnt(0)" ::: "memory");
  __syncthreads();  // X staged (all waves)

  // ---- phase 1: K, V^T for tokens [half*64, half*64+64) of this head ----
  // unroll 2: two independent build chains interleave (ds_read/MFMA/pack)
#pragma unroll 2
  for (int mt = 0; mt < 4; ++mt) {
    int tb = half * 64 + mt * 16;
    int arow = tb + l16; if (arow > 120) arow = 120;  // pad rows: any valid data
    bf16x8 a[4];
#pragma unroll
    for (int k = 0; k < 4; ++k)
      a[k] = *(const bf16x8*)(xl + arow * 128 + (((k * 4 + quad) ^ (arow & 7)) << 3));
#pragma unroll
    for (int nt = 0; nt < 2; ++nt) {
      f32x4 kacc = fz, vacc = fz;
      __builtin_amdgcn_s_setprio(1);
#pragma unroll
      for (int k = 0; k < 4; ++k) {
        kacc = mfma16(a[k], wkf[nt][k], kacc);
        vacc = mfma16(a[k], wvf[nt][k], vacc);
      }
      __builtin_amdgcn_s_setprio(0);
      int d = nt * 16 + l16;
      int kc = nt * 2 + (l16 >> 3);  // d>>3
#pragma unroll
      for (int r = 0; r < 4; ++r) {
        int t = tb + quad * 4 + r;
        Kh[t * 32 + ((kc ^ (t & 3)) << 3) + (l16 & 7)] = f2bf(kacc[r] + kb2[nt]);
      }
      float vv[4];
#pragma unroll
      for (int r = 0; r < 4; ++r) {
        int t = tb + quad * 4 + r;
        vv[r] = (t < NTOK) ? (vacc[r] + vb2[nt]) : 0.f;  // zero pad rows
      }
      // t>>3 and the swizzle slot are r-invariant: 4 consecutive u16 -> one b64
      u32x2 vp = { cvt_pk_bf16(vv[0], vv[1]), cvt_pk_bf16(vv[2], vv[3]) };
      *(u32x2*)(Vh + d * 128 + ((((tb >> 3) + (quad >> 1)) ^ l16) << 3) + (quad & 1) * 4) = vp;
    }
  }
  __syncthreads();  // K/V halves built by both waves of the head

  // ---- phase 2: 4 query M-tiles per wave, swapped operands ----
  // FULL unroll (r13): all 4 independent tiles visible -> scheduler can
  // overlap softmax VALU of tiles i,i+1 under MFMA/ds_read of i+2,i+3.
#pragma unroll 4
  for (int qmt = 0; qmt < 4; ++qmt) {
    int qb = (half * 4 + qmt) * 16;
    int qrow = qb + l16;
    int qrowc = qrow > 120 ? 120 : qrow;
    // B-frag of X query rows from staged LDS: lane = q-token column
    bf16x8 xb[4];
#pragma unroll
    for (int k = 0; k < 4; ++k)
      xb[k] = *(const bf16x8*)(xl + qrowc * 128 + (((k * 4 + quad) ^ (qrowc & 7)) << 3));
    // Q^T = WQ @ X^T: C col = q (l16), row = dim (nt*16 + quad*4 + r)
    f32x4 qv[2];
    __builtin_amdgcn_s_setprio(1);
#pragma unroll
    for (int nt = 0; nt < 2; ++nt) {
      f32x4 acc = fz;
#pragma unroll
      for (int k = 0; k < 4; ++k) acc = mfma16(wqf[nt][k], xb[k], acc);
      qv[nt] = acc;
    }
    __builtin_amdgcn_s_setprio(0);
    // pack Q to bf16 pairs and repack C-layout -> B-frag (lane=q, elems=dims)
    unsigned qpk[2][2];
#pragma unroll
    for (int nt = 0; nt < 2; ++nt)
#pragma unroll
      for (int r2 = 0; r2 < 2; ++r2)
        qpk[nt][r2] = cvt_pk_bf16((qv[nt][2 * r2] + qbias[nt][2 * r2]) * scl,
                                  (qv[nt][2 * r2 + 1] + qbias[nt][2 * r2 + 1]) * scl);
    u32x4 qu;
#pragma unroll
    for (int r2 = 0; r2 < 2; ++r2) {
      unsigned mlo, mhi;
      quad_repack(qpk[0][r2], qpk[1][r2], quad, mlo, mhi);
      qu[r2] = mlo; qu[2 + r2] = mhi;
    }
    bf16x8 qfrag = __builtin_bit_cast(bf16x8, qu);
    // S^T: rows = k-token (nt*16 + quad*4 + r), cols = q (l16)
    f32x4 lg[8];
    __builtin_amdgcn_s_setprio(1);
#pragma unroll
    for (int nt = 0; nt < 8; ++nt) {
      bf16x8 ka = *(const bf16x8*)(Kh + (nt * 16 + l16) * 32 + ((quad ^ (l16 & 3)) << 3));
      lg[nt] = mfma16(ka, qfrag, fz);
    }
    __builtin_amdgcn_s_setprio(0);
    // in-register softmax: per-lane 32 k-values + 2 cross-quad shuffles.
    // K rows 121..127 are clamped copies of row 120 -> max unchanged; their
    // exp terms are zeroed below (exact mask).
    f32x4 t0 = vmax4(vmax4(lg[0], lg[1]), vmax4(lg[2], lg[3]));
    f32x4 t1 = vmax4(vmax4(lg[4], lg[5]), vmax4(lg[6], lg[7]));
    f32x4 tm = vmax4(t0, t1);
    float mx = fmaxf(fmaxf(tm[0], tm[1]), fmaxf(tm[2], tm[3]));
    mx = fmaxf(mx, __shfl_xor(mx, 16));
    mx = fmaxf(mx, __shfl_xor(mx, 32));
#pragma unroll
    for (int nt = 0; nt < 8; ++nt)
#pragma unroll
      for (int r = 0; r < 4; ++r) {
        float ev = __builtin_amdgcn_exp2f(lg[nt][r] - mx);  // exp2-domain
        if (nt == 7 && (quad * 4 + r > 8)) ev = 0.f;        // k = 112+quad*4+r > 120
        lg[nt][r] = ev;
      }
    f32x4 s4 = (lg[0] + lg[1]) + (lg[2] + lg[3]) + ((lg[4] + lg[5]) + (lg[6] + lg[7]));
    float sum = (s4[0] + s4[1]) + (s4[2] + s4[3]);
    sum += __shfl_xor(sum, 16);
    sum += __shfl_xor(sum, 32);
    float rinv = __builtin_amdgcn_rcpf(sum);  // normalize deferred to O epilogue
    // P -> bf16 pairs: pk[nt][r2] = tokens (nt*16 + quad*4 + 2r2, +1)
    unsigned pk[8][2];
#pragma unroll
    for (int nt = 0; nt < 8; ++nt)
#pragma unroll
      for (int r2 = 0; r2 < 2; ++r2)
        pk[nt][r2] = cvt_pk_bf16(lg[nt][2 * r2], lg[nt][2 * r2 + 1]);
    // O^T = V^T @ P: per 32-token k-step, repack P to B-frag and MFMA
    f32x4 oacc[2] = {fz, fz};
#pragma unroll
    for (int s = 0; s < 4; ++s) {
      u32x4 pu;
#pragma unroll
      for (int r2 = 0; r2 < 2; ++r2) {
        unsigned mlo, mhi;
        quad_repack(pk[2 * s][r2], pk[2 * s + 1][r2], quad, mlo, mhi);
        pu[r2] = mlo; pu[2 + r2] = mhi;
      }
      bf16x8 pfrag = __builtin_bit_cast(bf16x8, pu);
      __builtin_amdgcn_s_setprio(1);
#pragma unroll
      for (int mt = 0; mt < 2; ++mt) {
        bf16x8 va = *(const bf16x8*)(Vh + (mt * 16 + l16) * 128 + (((s * 4 + quad) ^ l16) << 3));
        oacc[mt] = mfma16(va, pfrag, oacc[mt]);
      }
      __builtin_amdgcn_s_setprio(0);
    }
    // epilogue: C col = q (l16), row = dim (mt*16 + quad*4 + r); pack dim-pairs
    if (qrow < NTOK) {
      u16* Op = O + (size_t)seq * (NTOK * HD) + (size_t)qrow * HD + head * 32;
#pragma unroll
      for (int mt = 0; mt < 2; ++mt) {
        u32x2 w = { cvt_pk_bf16(oacc[mt][0] * rinv, oacc[mt][1] * rinv),
                    cvt_pk_bf16(oacc[mt][2] * rinv, oacc[mt][3] * rinv) };
        *(u32x2*)(Op + mt * 16 + quad * 4) = w;
      }
    }
  }
}

// ---------------- fused proj+LN1+ff1+ff2+LN2, channel-partitioned ---------
// Block = 128 token-rows (1936 blocks, r11 config). Wave w owns out-channels
// [32w,32w+32) for proj, ff1, ff2: 24 weight frags hoisted once, loaded
// under the stage wait. Each wave covers all 128 tokens (8 groups of 16).
// LN via 4KB partial-sum LDS. 5 barriers. 2 WG/CU (proven optimum; r12's
// 64-token/3WG variant regressed on per-block fixed costs).
__global__ __launch_bounds__(256, 2) void blockln_kernel(
    u16* __restrict__ X, const u16* __restrict__ O,
    const u16* __restrict__ WP, const float* __restrict__ PB,
    const u16* __restrict__ W1, const float* __restrict__ B1,
    const u16* __restrict__ W2, const float* __restrict__ B2,
    const float* __restrict__ G1, const float* __restrict__ Bt1,
    const float* __restrict__ G2, const float* __restrict__ Bt2, int layer) {
  __shared__ u16 as_[128 * 128];   // staged O -> LN1 output
  __shared__ u16 xr[128 * 128];    // staged X residual -> relu(ff1)
  __shared__ float part[1024];     // per-(token, wave) LN partials (sum, ssq)
  int r0 = blockIdx.x * 128, tid = threadIdx.x;
  int wave = tid >> 6, lane = tid & 63, l16 = lane & 15, quad = lane >> 4;
  const f32x4 fz = {0.f, 0.f, 0.f, 0.f};
  const int Lb = layer * 128;
  const int ch0 = wave * 32;          // this wave's output channels
  const int ch8b = wave * 4 + (quad >> 1);  // 16B-chunk base for (wave, quad)

  // ---- stage O and X (16B chunk c of row r at slot c^(r&7)) ----
  {
    const char* Ob = (const char*)(O + (size_t)r0 * HD);
    const char* Xb = (const char*)(X + (size_t)r0 * HD);
#pragma unroll
    for (int j = 0; j < 8; ++j) {
      int n = wave * 512 + j * 64 + lane;  // 16B chunk index (2048 per buffer)
      int r = n >> 4, c = n & 15;
      int gsrc = r * 256 + ((c ^ (r & 7)) << 4);
      stage16(Ob + gsrc, (void*)(as_ + (wave * 512 + j * 64) * 8));
      stage16(Xb + gsrc, (void*)(xr + (wave * 512 + j * 64) * 8));
    }
  }
  // hoist this wave's weight frags for all 3 GEMMs (latency hides under stage)
  bf16x8 wpf[2][4], w1f[2][4], w2f[2][4];
#pragma unroll
  for (int g = 0; g < 2; ++g)
#pragma unroll
    for (int k = 0; k < 4; ++k) {
      size_t off = (size_t)(Lb + ch0 + g * 16 + l16) * HD + k * 32 + quad * 8;
      wpf[g][k] = *(const bf16x8*)(WP + off);
      w1f[g][k] = *(const bf16x8*)(W1 + off);
      w2f[g][k] = *(const bf16x8*)(W2 + off);
    }
  asm volatile("s_waitcnt vmcnt(0)" ::: "memory");
  __syncthreads();  // B1: staged

  // ---- proj (+PB, +X residual) over all 8 token groups; LN1 partials ----
  f32x4 acc[2][8];
#pragma unroll
  for (int mt = 0; mt < 8; ++mt) {
    int tok = mt * 16 + l16;
    bf16x8 of[4];
#pragma unroll
    for (int k = 0; k < 4; ++k)
      of[k] = *(const bf16x8*)(as_ + tok * 128 + (((k * 4 + quad) ^ (tok & 7)) << 3));
    __builtin_amdgcn_s_setprio(1);
#pragma unroll
    for (int g = 0; g < 2; ++g) {
      f32x4 a = fz;
#pragma unroll
      for (int k = 0; k < 4; ++k) a = mfma16(wpf[g][k], of[k], a);
      acc[g][mt] = a;
    }
    __builtin_amdgcn_s_setprio(0);
    float sum = 0.f, ssq = 0.f;
#pragma unroll
    for (int g = 0; g < 2; ++g) {
      float4 pb4 = *(const float4*)(PB + Lb + ch0 + g * 16 + quad * 4);
      int sl = (ch8b + g * 2) ^ (tok & 7);
      u32x2 xw = *(const u32x2*)(xr + tok * 128 + (sl << 3) + (quad & 1) * 4);
      acc[g][mt][0] += pb4.x + bfu32lo(xw[0]);
      acc[g][mt][1] += pb4.y + bfu32hi(xw[0]);
      acc[g][mt][2] += pb4.z + bfu32lo(xw[1]);
      acc[g][mt][3] += pb4.w + bfu32hi(xw[1]);
#pragma unroll
      for (int r = 0; r < 4; ++r) { sum += acc[g][mt][r]; ssq += acc[g][mt][r] * acc[g][mt][r]; }
    }
    sum += __shfl_xor(sum, 16); ssq += __shfl_xor(ssq, 16);
    sum += __shfl_xor(sum, 32); ssq += __shfl_xor(ssq, 32);
    if (quad == 0) *(float2*)(part + ((mt * 4 + wave) * 16 + l16) * 2) = make_float2(sum, ssq);
  }
  __syncthreads();  // B2: LN1 partials visible

  // ---- LN1 apply -> as_ (overwrites O stage; same swizzle) ----
#pragma unroll
  for (int mt = 0; mt < 8; ++mt) {
    int tok = mt * 16 + l16;
    float sum = 0.f, ssq = 0.f;
#pragma unroll
    for (int ww = 0; ww < 4; ++ww) {
      float2 p = *(const float2*)(part + ((mt * 4 + ww) * 16 + l16) * 2);
      sum += p.x; ssq += p.y;
    }
    float mean = sum * (1.f / 128.f);
    float rstd = rsqrtf(ssq * (1.f / 128.f) - mean * mean + EPSF);
#pragma unroll
    for (int g = 0; g < 2; ++g) {
      float4 g4 = *(const float4*)(G1 + Lb + ch0 + g * 16 + quad * 4);
      float4 b4 = *(const float4*)(Bt1 + Lb + ch0 + g * 16 + quad * 4);
      u32x2 wv = { cvt_pk_bf16((acc[g][mt][0] - mean) * rstd * g4.x + b4.x,
                               (acc[g][mt][1] - mean) * rstd * g4.y + b4.y),
                   cvt_pk_bf16((acc[g][mt][2] - mean) * rstd * g4.z + b4.z,
                               (acc[g][mt][3] - mean) * rstd * g4.w + b4.w) };
      int sl = (ch8b + g * 2) ^ (tok & 7);
      *(u32x2*)(as_ + tok * 128 + (sl << 3) + (quad & 1) * 4) = wv;
    }
  }
  __syncthreads();  // B3: LN1 out complete

  // ---- ff1 + relu(+B1) -> xr (overwrites X stage) ----
#pragma unroll
  for (int mt = 0; mt < 8; ++mt) {
    int tok = mt * 16 + l16;
    bf16x8 af[4];
#pragma unroll
    for (int k = 0; k < 4; ++k)
      af[k] = *(const bf16x8*)(as_ + tok * 128 + (((k * 4 + quad) ^ (tok & 7)) << 3));
    __builtin_amdgcn_s_setprio(1);
#pragma unroll
    for (int g = 0; g < 2; ++g) {
      f32x4 a = fz;
#pragma unroll
      for (int k = 0; k < 4; ++k) a = mfma16(w1f[g][k], af[k], a);
      float4 b14 = *(const float4*)(B1 + Lb + ch0 + g * 16 + quad * 4);
      u32x2 wv = { cvt_pk_bf16(fmaxf(a[0] + b14.x, 0.f), fmaxf(a[1] + b14.y, 0.f)),
                   cvt_pk_bf16(fmaxf(a[2] + b14.z, 0.f), fmaxf(a[3] + b14.w, 0.f)) };
      int sl = (ch8b + g * 2) ^ (tok & 7);
      *(u32x2*)(xr + tok * 128 + (sl << 3) + (quad & 1) * 4) = wv;
    }
    __builtin_amdgcn_s_setprio(0);
  }
  __syncthreads();  // B4: H complete

  // ---- ff2 (+B2, +LN1out residual); LN2 partials ----
#pragma unroll
  for (int mt = 0; mt < 8; ++mt) {
    int tok = mt * 16 + l16;
    bf16x8 hf[4];
#pragma unroll
    for (int k = 0; k < 4; ++k)
      hf[k] = *(const bf16x8*)(xr + tok * 128 + (((k * 4 + quad) ^ (tok & 7)) << 3));
    __builtin_amdgcn_s_setprio(1);
#pragma unroll
    for (int g = 0; g < 2; ++g) {
      f32x4 a = fz;
#pragma unroll
      for (int k = 0; k < 4; ++k) a = mfma16(w2f[g][k], hf[k], a);
      acc[g][mt] = a;
    }
    __builtin_amdgcn_s_setprio(0);
    float sum = 0.f, ssq = 0.f;
#pragma unroll
    for (int g = 0; g < 2; ++g) {
      float4 b24 = *(const float4*)(B2 + Lb + ch0 + g * 16 + quad * 4);
      int sl = (ch8b + g * 2) ^ (tok & 7);
      u32x2 lw = *(const u32x2*)(as_ + tok * 128 + (sl << 3) + (quad & 1) * 4);
      acc[g][mt][0] += b24.x + bfu32lo(lw[0]);
      acc[g][mt][1] += b24.y + bfu32hi(lw[0]);
      acc[g][mt][2] += b24.z + bfu32lo(lw[1]);
      acc[g][mt][3] += b24.w + bfu32hi(lw[1]);
#pragma unroll
      for (int r = 0; r < 4; ++r) { sum += acc[g][mt][r]; ssq += acc[g][mt][r] * acc[g][mt][r]; }
    }
    sum += __shfl_xor(sum, 16); ssq += __shfl_xor(ssq, 16);
    sum += __shfl_xor(sum, 32); ssq += __shfl_xor(ssq, 32);
    if (quad == 0) *(float2*)(part + ((mt * 4 + wave) * 16 + l16) * 2) = make_float2(sum, ssq);
  }
  __syncthreads();  // B5: LN2 partials visible

  // ---- LN2 apply -> X (b64 global stores) ----
#pragma unroll
  for (int mt = 0; mt < 8; ++mt) {
    int tok = mt * 16 + l16;
    float sum = 0.f, ssq = 0.f;
#pragma unroll
    for (int ww = 0; ww < 4; ++ww) {
      float2 p = *(const float2*)(part + ((mt * 4 + ww) * 16 + l16) * 2);
      sum += p.x; ssq += p.y;
    }
    float mean = sum * (1.f / 128.f);
    float rstd = rsqrtf(ssq * (1.f / 128.f) - mean * mean + EPSF);
    u16* Xp = X + (size_t)(r0 + tok) * HD + ch0;
#pragma unroll
    for (int g = 0; g < 2; ++g) {
      float4 g4 = *(const float4*)(G2 + Lb + ch0 + g * 16 + quad * 4);
      float4 b4 = *(const float4*)(Bt2 + Lb + ch0 + g * 16 + quad * 4);
      u32x2 wv = { cvt_pk_bf16((acc[g][mt][0] - mean) * rstd * g4.x + b4.x,
                               (acc[g][mt][1] - mean) * rstd * g4.y + b4.y),
                   cvt_pk_bf16((acc[g][mt][2] - mean) * rstd * g4.z + b4.z,
                               (acc[g][mt][3] - mean) * rstd * g4.w + b4.w) };
      *(u32x2*)(Xp + g * 16 + quad * 4) = wv;
    }
  }
}

// ---------------- final GEMM (M=2048,K=15488,N=256), split-K=16 ----------
// 512 1D blocks, XCD-chunked: swz=(bid&7)*64+(bid>>3) -> XCD k owns the
// contiguous work range [64k,64k+64) = all 32 m-tiles of j in {2k,2k+1}.
__global__ __launch_bounds__(256, 2) void outgemm_kernel(
    const u16* __restrict__ X, const u16* __restrict__ WO, float* __restrict__ PART) {
  __shared__ u16 as_[64 * 136];
  int bid = blockIdx.x;
  int swz = (bid & 7) * 64 + (bid >> 3);   // bijective: 512 = 8 * 64
  int mtile = swz & 31, j = swz >> 5;
  int tid = threadIdx.x, wave = tid >> 6, lane = tid & 63, l16 = lane & 15, quad = lane >> 4;
  int s0 = mtile * 64;
  int k0 = (j * 484) / 16, k1 = ((j + 1) * 484) / 16;  // k-steps of 32 over K=15488
  const f32x4 fz = {0.f, 0.f, 0.f, 0.f};
  f32x4 acc[4][4];
  for (int a = 0; a < 4; ++a) for (int b = 0; b < 4; ++b) acc[a][b] = fz;
  for (int kb = k0; kb < k1; kb += 4) {
    int nst = (k1 - kb < 4) ? (k1 - kb) : 4;
    __syncthreads();
    int chunks = 64 * 4 * nst;
    for (int c = tid; c < chunks; c += 256) {
      int row = c / (4 * nst), g = c % (4 * nst);
      *(uint4*)(as_ + row * 136 + g * 8) =
          *(const uint4*)(X + (size_t)(s0 + row) * 15488 + kb * 32 + g * 8);
    }
    __syncthreads();
    for (int kk = 0; kk < nst; ++kk) {
      bf16x8 af[4];
#pragma unroll
      for (int mt = 0; mt < 4; ++mt)
        af[mt] = *(const bf16x8*)(as_ + (mt * 16 + l16) * 136 + kk * 32 + quad * 8);
#pragma unroll
      for (int n = 0; n < 4; ++n) {
        int nt = wave * 4 + n;
        bf16x8 bf = *(const bf16x8*)(WO + (size_t)(nt * 16 + l16) * 15488 +
                                     (size_t)(kb + kk) * 32 + quad * 8);
#pragma unroll
        for (int mt = 0; mt < 4; ++mt) acc[mt][n] = mfma16(af[mt], bf, acc[mt][n]);
      }
    }
  }
  for (int mt = 0; mt < 4; ++mt)
    for (int n = 0; n < 4; ++n) {
      int nt = wave * 4 + n;
#pragma unroll
      for (int r = 0; r < 4; ++r) {
        int row = s0 + mt * 16 + quad * 4 + r;
        PART[((size_t)j * 2048 + row) * 256 + nt * 16 + l16] = acc[mt][n][r];
      }
    }
}

// ---------------- reduce split-K partials + bias + final LN --------------
__global__ __launch_bounds__(256) void lnf_kernel(
    const float* __restrict__ PART, const float* __restrict__ BO,
    const float* __restrict__ G, const float* __restrict__ Bt, float* __restrict__ OUT) {
  int s = blockIdx.x * 4 + (threadIdx.x >> 6);  // one wave per sequence
  int lane = threadIdx.x & 63;
  float v[4], sum = 0.f, ssq = 0.f;
#pragma unroll
  for (int i = 0; i < 4; ++i) {
    int c = lane + i * 64;
    float t = BO[c];
    for (int jj = 0; jj < 16; ++jj) t += PART[((size_t)jj * 2048 + s) * 256 + c];
    v[i] = t; sum += t; ssq += t * t;
  }
  for (int m = 1; m <= 32; m <<= 1) { sum += __shfl_xor(sum, m, 64); ssq += __shfl_xor(ssq, m, 64); }
  float mean = sum * (1.f / 256.f);
  float var = ssq * (1.f / 256.f) - mean * mean;
  float rstd = rsqrtf(var + EPSF);
#pragma unroll
  for (int i = 0; i < 4; ++i) {
    int c = lane + i * 64;
    OUT[(size_t)s * 256 + c] = (v[i] - mean) * rstd * G[c] + Bt[c];
  }
}

extern "C" void kernel_launch(void* const* d_in, const int* in_sizes, int n_in,
                              void* d_out, int out_size, void* d_ws, size_t ws_size,
                              hipStream_t stream) {
  const float* forest = (const float*)d_in[0];
  const int* adj      = (const int*)d_in[1];
  const int* perm     = (const int*)d_in[2];
  const float* w_in   = (const float*)d_in[3];
  const float* b_in   = (const float*)d_in[4];
  const float* qkv_w  = (const float*)d_in[5];
  const float* qkv_b  = (const float*)d_in[6];
  const float* proj_w = (const float*)d_in[7];
  const float* proj_b = (const float*)d_in[8];
  const float* ff1_w  = (const float*)d_in[9];
  const float* ff1_b  = (const float*)d_in[10];
  const float* ff2_w  = (const float*)d_in[11];
  const float* ff2_b  = (const float*)d_in[12];
  const float* ln1_g  = (const float*)d_in[13];
  const float* ln1_b  = (const float*)d_in[14];
  const float* ln2_g  = (const float*)d_in[15];
  const float* ln2_b  = (const float*)d_in[16];
  const float* w_out  = (const float*)d_in[17];
  const float* b_out  = (const float*)d_in[18];
  const float* lnf_g  = (const float*)d_in[19];
  const float* lnf_b  = (const float*)d_in[20];

  // workspace map (bytes): bf16 weights 8,323,072 | X 63,438,848 | O 63,438,848 | PART 33,554,432
  char* ws = (char*)d_ws;
  u16* WB = (u16*)ws;
  u16* X  = (u16*)(ws + 8323072);
  u16* O  = (u16*)(ws + 8323072 + 63438848);
  float* PART = (float*)(ws + 8323072 + 2 * (size_t)63438848);

  u16* WQKV  = WB;
  u16* WPROJ = WB + 98304;
  u16* WFF1  = WB + 131072;
  u16* WFF2  = WB + 163840;
  u16* WOUT  = WB + 196608;

  convw_kernel<<<4064, 256, 0, stream>>>(qkv_w, proj_w, ff1_w, ff2_w, w_out, WB);
  inproj_kernel<<<2048, 256, 0, stream>>>(forest, adj, perm, w_in, b_in, X);
  for (int layer = 0; layer < 2; ++layer) {
    attn_kernel<<<4096, 256, 0, stream>>>(X, O, WQKV, qkv_b, layer);
    blockln_kernel<<<1936, 256, 0, stream>>>(X, O, WPROJ, proj_b, WFF1, ff1_b,
                                             WFF2, ff2_b, ln1_g, ln1_b, ln2_g, ln2_b, layer);
  }
  outgemm_kernel<<<512, 256, 0, stream>>>(X, WOUT, PART);
  lnf_kernel<<<512, 256, 0, stream>>>(PART, b_out, lnf_g, lnf_b, (float*)d_out);
}